// Round 2
// baseline (30235.931 us; speedup 1.0000x reference)
//
#include <hip/hip_runtime.h>

#define T_STEPS 256
#define NBATCH  256
#define HID     1024
#define KTOT    2048

typedef short bf16x8 __attribute__((ext_vector_type(8)));
typedef float f32x4  __attribute__((ext_vector_type(4)));

__device__ inline short cvt_bf16(float f) {
  unsigned u = __builtin_bit_cast(unsigned, f);
  u += 0x7fffu + ((u >> 16) & 1u);   // round-to-nearest-even
  return (short)(u >> 16);
}

__device__ inline float fast_sigmoid(float x) {
  return __builtin_amdgcn_rcpf(1.0f + __builtin_amdgcn_exp2f(-1.44269504f * x));
}
__device__ inline float fast_tanh(float x) {
  return 2.0f * __builtin_amdgcn_rcpf(1.0f + __builtin_amdgcn_exp2f(-2.88539008f * x)) - 1.0f;
}

// ---------------------------------------------------------------------------
// Tiled layouts (MFMA-fragment contiguous):
//   Wbig: [ug 64][k32 64][ui 4][lane 64][8]  (lane = kq*16 + uu, elems j=k&7)
//   x:    [mtile 16][k32 64][lane 64][8]     (lane = kq*16 + mrow)
// Logical row permutation: u' = ug*64 + g*16 + uu.
// ---------------------------------------------------------------------------

// ---- K1: Whh -> Wbig right half (tiled); Wfc cast; x0 build ---------------
__global__ void cast_kernel(const float* __restrict__ Whh,
                            const float* __restrict__ Wfc,
                            const float* __restrict__ cvec,
                            short* __restrict__ Wbig,
                            short* __restrict__ Wfcb,
                            short* __restrict__ x0) {
  long i = (long)blockIdx.x * blockDim.x + threadIdx.x;   // float4 quad index
  const long nWhh = 4096L * 1024 / 4;   // 1048576
  const long nWfc = 1024L * 1024 / 4;   // 262144
  const long nX0  = 256L * KTOT / 4;    // 131072
  if (i < nWhh) {
    int in_row = (int)(i >> 8);
    int c4 = ((int)i & 255) * 4;
    int g = in_row >> 10, rem = in_row & 1023, ug = rem >> 4, uu = rem & 15;
    int k = 1024 + c4;                  // right half of K
    int k32 = k >> 5, kq = (k >> 3) & 3, j = k & 7;
    float4 v = *(const float4*)(Whh + (long)in_row * 1024 + c4);
    short4 o;
    o.x = cvt_bf16(v.x); o.y = cvt_bf16(v.y); o.z = cvt_bf16(v.z); o.w = cvt_bf16(v.w);
    long dst = ((((long)(ug * 64 + k32) * 4 + g) * 64) + kq * 16 + uu) * 8 + j;
    *(short4*)(Wbig + dst) = o;
  } else if (i < nWhh + nWfc) {
    long q = i - nWhh;
    float4 v = ((const float4*)Wfc)[q];
    short4 o;
    o.x = cvt_bf16(v.x); o.y = cvt_bf16(v.y); o.z = cvt_bf16(v.z); o.w = cvt_bf16(v.w);
    *(short4*)(Wfcb + q * 4) = o;
  } else if (i < nWhh + nWfc + nX0) {
    long q = i - nWhh - nWfc;
    int m = (int)(q >> 9);              // 512 quads per 2048-col row
    int c4 = ((int)q & 511) * 4;
    short4 o;
    if (c4 < 1024) {                    // c-part is zero at t=0 (i0 = 0 fold)
      o.x = o.y = o.z = o.w = 0;
    } else {
      float4 v = *(const float4*)(cvec + (long)m * 1024 + (c4 - 1024));
      o.x = cvt_bf16(v.x); o.y = cvt_bf16(v.y); o.z = cvt_bf16(v.z); o.w = cvt_bf16(v.w);
    }
    int k32 = c4 >> 5, kq = (c4 >> 3) & 3, j = c4 & 7;
    int mtile = m >> 4, mrow = m & 15;
    long dst = (((long)mtile * 64 + k32) * 64 + kq * 16 + mrow) * 8 + j;
    *(short4*)(x0 + dst) = o;
  }
}

// ---- K2: b0 = b_ih+b_hh ; bc = b0 + W_ih @ b_fc  (permuted to u') ---------
__global__ void bias_kernel(const float* __restrict__ W_ih,
                            const float* __restrict__ b_ih,
                            const float* __restrict__ b_hh,
                            const float* __restrict__ b_fc,
                            float* __restrict__ b0r, float* __restrict__ bcr) {
  int w = threadIdx.x >> 6, l = threadIdx.x & 63;
  int n = blockIdx.x * 4 + w;          // 4096 rows, 4 waves/block
  const float* row = W_ih + (long)n * HID;
  float s = 0.f;
  for (int i = l; i < HID; i += 64) s += row[i] * b_fc[i];
  #pragma unroll
  for (int off = 32; off; off >>= 1) s += __shfl_xor(s, off, 64);
  if (l == 0) {
    int g = n >> 10, uidx = n & 1023, ug = uidx >> 4, uu = uidx & 15;
    int up = ug * 64 + g * 16 + uu;
    float base = b_ih[n] + b_hh[n];
    b0r[up] = base;
    bcr[up] = base + s;
  }
}

// ---- K3: Wc = W_ih @ W_fc -> Wbig left half (tiled, bf16) -----------------
__global__ void wc_kernel(const float* __restrict__ W_ih,
                          const float* __restrict__ W_fc,
                          short* __restrict__ Wbig) {
  int w = threadIdx.x >> 6, l = threadIdx.x & 63;
  int tile = blockIdx.x * 4 + w;       // 16384 tiles: 256 n-tiles x 64 k-tiles
  int nt = tile >> 6, kt = tile & 63;
  int lr = l & 15, lq = l >> 4;
  f32x4 acc = {0.f, 0.f, 0.f, 0.f};
  const float* arow = W_ih + (long)(nt * 16 + lr) * HID + lq * 8;
  const float* bcol = W_fc + (long)(lq * 8) * HID + kt * 16 + lr;
  for (int jc = 0; jc < HID; jc += 32) {
    float4 a0 = *(const float4*)(arow + jc);
    float4 a1 = *(const float4*)(arow + jc + 4);
    bf16x8 a;
    a[0]=cvt_bf16(a0.x); a[1]=cvt_bf16(a0.y); a[2]=cvt_bf16(a0.z); a[3]=cvt_bf16(a0.w);
    a[4]=cvt_bf16(a1.x); a[5]=cvt_bf16(a1.y); a[6]=cvt_bf16(a1.z); a[7]=cvt_bf16(a1.w);
    bf16x8 b;
    #pragma unroll
    for (int jj = 0; jj < 8; ++jj) b[jj] = cvt_bf16(bcol[(long)(jc + jj) * HID]);
    acc = __builtin_amdgcn_mfma_f32_16x16x32_bf16(a, b, acc, 0, 0, 0);
  }
  int k = kt * 16 + lr;                // col in [0,1024) -> left half of K
  int g = nt >> 6, ug = nt & 63;
  int k32 = k >> 5, kq = (k >> 3) & 3, j = k & 7;
  #pragma unroll
  for (int r = 0; r < 4; ++r) {
    long dst = ((((long)(ug * 64 + k32) * 4 + g) * 64) + kq * 16 + (lq * 4 + r)) * 8 + j;
    Wbig[dst] = cvt_bf16(acc[r]);
  }
}

// ---- persistent LSTM kernel: all 256 steps in one dispatch ----------------
// 256 blocks (1/CU via 144KB LDS) x 512 threads (8 waves = 4 mt x 2 kh).
// Block owns (mg, ug): 64 batch rows x 16 units (64 gate cols).
// B c-half (K 0..1023) pinned in LDS; B h-half streamed from L2.
// Cell state + biases live in registers for all 256 steps.
// Per-step sync: 4 independent 64-block ticket barriers (one per mg-group).
__global__ __launch_bounds__(512, 2)
void lstm_kernel(const short* __restrict__ Wbig,
                 const float* __restrict__ b0r,
                 const float* __restrict__ bcr,
                 const float* __restrict__ cvec,
                 short* __restrict__ xb0, short* __restrict__ xb1,
                 float* __restrict__ hst, float* __restrict__ cst,
                 unsigned* __restrict__ ctr) {
  __shared__ __align__(16) short bpin[32 * 4 * 64 * 8];   // 128 KB: B c-half
  __shared__ f32x4 redbuf[4 * 4 * 64];                    // 16 KB split-K buf

  const int tid = threadIdx.x;
  const int w = tid >> 6, l = tid & 63, lr = l & 15, lq = l >> 4;
  const int mt = w & 3, kh = w >> 2;
  const int b = blockIdx.x;
  const int ug = (b & 7) * 8 + ((b >> 3) & 7);   // XCD-contiguous weight stripes
  const int mg = b >> 6;

  // pin B c-half (k32 0..31 of this ug slab = first 128KB, contiguous)
  {
    const int4* s = (const int4*)(Wbig + (long)ug * 131072);
    int4* d = (int4*)bpin;
    for (int i = tid; i < 8192; i += 512) d[i] = s[i];
  }

  // biases (both t=0 and t>0 variants) + initial cell state in registers
  const int unit = ug * 16 + lr;
  float c_old[4] = {0.f, 0.f, 0.f, 0.f};
  float bia[4] = {}, bib[4] = {};
  if (kh == 0) {
    #pragma unroll
    for (int gi = 0; gi < 4; ++gi) {
      bia[gi] = b0r[ug * 64 + gi * 16 + lr];
      bib[gi] = bcr[ug * 64 + gi * 16 + lr];
    }
    #pragma unroll
    for (int r = 0; r < 4; ++r) {
      int m = mg * 64 + mt * 16 + lq * 4 + r;
      c_old[r] = cvec[(long)m * HID + unit];
    }
  }
  __syncthreads();

  // xnext write base (epilogue lanes): c-half col = unit, h-half = +16384
  const int mtile_e = mg * 4 + mt;
  const int k32c = ug >> 1;
  const int kqc = (ug & 1) * 2 + (lr >> 3);
  const int jc = lr & 7;
  const long xwbase = (((long)mtile_e * 64 + k32c) * 64 + kqc * 16) * 8 + jc;

  // A/B fragment bases
  const long abase_off = ((long)(mg * 4 + mt) * 64 + kh * 32) * 512 + l * 8;
  const short* gB = Wbig + (((long)ug * 64 + 32) * 4) * 512 + l * 8;  // kh=1
  const short* lB = bpin + l * 8;                                     // kh=0

  #pragma unroll 1
  for (int t = 0; t < T_STEPS; ++t) {
    const short* xc = (t & 1) ? xb1 : xb0;
    short* xn = (t & 1) ? xb0 : xb1;
    const short* ab = xc + abase_off;

    f32x4 acc[4] = {{0,0,0,0},{0,0,0,0},{0,0,0,0},{0,0,0,0}};
    bf16x8 a2[2], bf2[2][4];
    a2[0] = *(const bf16x8*)(ab);
    if (kh) {
      #pragma unroll
      for (int u = 0; u < 4; ++u) bf2[0][u] = *(const bf16x8*)(gB + (long)u * 512);
    } else {
      #pragma unroll
      for (int u = 0; u < 4; ++u) bf2[0][u] = *(const bf16x8*)(lB + (long)u * 512);
    }
    #pragma unroll
    for (int it = 0; it < 32; ++it) {
      const int cu = it & 1, nx = cu ^ 1;
      if (it < 31) {
        a2[nx] = *(const bf16x8*)(ab + (long)(it + 1) * 512);
        if (kh) {
          #pragma unroll
          for (int u = 0; u < 4; ++u)
            bf2[nx][u] = *(const bf16x8*)(gB + (long)(it + 1) * 2048 + (long)u * 512);
        } else {
          #pragma unroll
          for (int u = 0; u < 4; ++u)
            bf2[nx][u] = *(const bf16x8*)(lB + (long)(it + 1) * 2048 + (long)u * 512);
        }
      }
      #pragma unroll
      for (int u = 0; u < 4; ++u)
        acc[u] = __builtin_amdgcn_mfma_f32_16x16x32_bf16(a2[cu], bf2[cu][u], acc[u], 0, 0, 0);
    }

    // split-K=2 reduction
    if (kh) {
      #pragma unroll
      for (int u = 0; u < 4; ++u) redbuf[(mt * 4 + u) * 64 + l] = acc[u];
    }
    __syncthreads();
    if (kh == 0) {
      #pragma unroll
      for (int u = 0; u < 4; ++u) acc[u] += redbuf[(mt * 4 + u) * 64 + l];

      const float biv = (t == 0) ? bia[0] : bib[0];
      const float bfv = (t == 0) ? bia[1] : bib[1];
      const float bgv = (t == 0) ? bia[2] : bib[2];
      const float bov = (t == 0) ? bia[3] : bib[3];
      #pragma unroll
      for (int r = 0; r < 4; ++r) {
        float ig = fast_sigmoid(acc[0][r] + biv);
        float fg = fast_sigmoid(acc[1][r] + bfv);
        float gg = fast_tanh(acc[2][r] + bgv);
        float og = fast_sigmoid(acc[3][r] + bov);
        float cn = fg * c_old[r] + ig * gg;
        float hn = og * fast_tanh(cn);
        c_old[r] = cn;
        int m = mg * 64 + mt * 16 + lq * 4 + r;
        long o = ((long)m * T_STEPS + t) * HID + unit;
        __builtin_nontemporal_store(hn, &hst[o]);   // outputs: bypass L2
        __builtin_nontemporal_store(cn, &cst[o]);
        int mrow = lq * 4 + r;
        xn[xwbase + (long)mrow * 8]         = cvt_bf16(cn);  // c-half
        xn[xwbase + (long)mrow * 8 + 16384] = cvt_bf16(hn);  // h-half
      }
    }

    if (t < T_STEPS - 1) {
      __threadfence();       // release: flush xnext to coherence point (wbL2)
      __syncthreads();
      if (tid == 0) {
        __hip_atomic_fetch_add(&ctr[mg * 16], 1u, __ATOMIC_RELEASE,
                               __HIP_MEMORY_SCOPE_AGENT);
        unsigned tgt = 64u * (unsigned)(t + 1);
        while (__hip_atomic_load(&ctr[mg * 16], __ATOMIC_ACQUIRE,
                                 __HIP_MEMORY_SCOPE_AGENT) < tgt)
          __builtin_amdgcn_s_sleep(8);
      }
      __syncthreads();
      __threadfence();       // acquire: invalidate stale L2/L1 x lines
    }
  }
}

// ---- K4: outputs = c_states @ W_fc.T + b_fc  (A read fp32 from cst) -------
__global__ void fc_kernel(const float* __restrict__ A,      // [65536,1024]
                          const short* __restrict__ Bw,     // W_fc bf16
                          const float* __restrict__ b_fc,
                          float* __restrict__ out) {
  int w = threadIdx.x >> 6, l = threadIdx.x & 63;
  int wave = blockIdx.x * 4 + w;       // 16384 waves: 1024 m-tiles x 16 u-tiles
  int ut = wave & 15, mt = wave >> 4;
  int lr = l & 15, lq = l >> 4;
  f32x4 acc[4][4] = {};
  const float* arow[4]; const short* brow[4];
  #pragma unroll
  for (int i = 0; i < 4; ++i) {
    arow[i] = A  + (long)(mt * 64 + i * 16 + lr) * HID + lq * 8;
    brow[i] = Bw + (long)(ut * 64 + i * 16 + lr) * HID + lq * 8;
  }
  for (int kc = 0; kc < HID; kc += 32) {
    bf16x8 a[4], b[4];
    #pragma unroll
    for (int i = 0; i < 4; ++i) {
      float4 v0 = *(const float4*)(arow[i] + kc);
      float4 v1 = *(const float4*)(arow[i] + kc + 4);
      bf16x8 r;
      r[0]=cvt_bf16(v0.x); r[1]=cvt_bf16(v0.y); r[2]=cvt_bf16(v0.z); r[3]=cvt_bf16(v0.w);
      r[4]=cvt_bf16(v1.x); r[5]=cvt_bf16(v1.y); r[6]=cvt_bf16(v1.z); r[7]=cvt_bf16(v1.w);
      a[i] = r;
      b[i] = *(const bf16x8*)(brow[i] + kc);
    }
    #pragma unroll
    for (int mi = 0; mi < 4; ++mi)
      #pragma unroll
      for (int ui = 0; ui < 4; ++ui)
        acc[mi][ui] = __builtin_amdgcn_mfma_f32_16x16x32_bf16(a[mi], b[ui], acc[mi][ui], 0, 0, 0);
  }
  int u0 = ut * 64;
  #pragma unroll
  for (int ui = 0; ui < 4; ++ui) {
    float bf = b_fc[u0 + ui * 16 + lr];
    #pragma unroll
    for (int mi = 0; mi < 4; ++mi)
      #pragma unroll
      for (int r = 0; r < 4; ++r) {
        long mo = (long)mt * 64 + mi * 16 + lq * 4 + r;
        __builtin_nontemporal_store(acc[mi][ui][r] + bf,
                                    &out[mo * HID + u0 + ui * 16 + lr]);
      }
  }
}

// ---------------------------------------------------------------------------
extern "C" void kernel_launch(void* const* d_in, const int* in_sizes, int n_in,
                              void* d_out, int out_size, void* d_ws, size_t ws_size,
                              hipStream_t stream) {
  const float* cvec = (const float*)d_in[0];
  const float* W_ih = (const float*)d_in[1];
  const float* W_hh = (const float*)d_in[2];
  const float* b_ih = (const float*)d_in[3];
  const float* b_hh = (const float*)d_in[4];
  const float* W_fc = (const float*)d_in[5];
  const float* b_fc = (const float*)d_in[6];
  float* out = (float*)d_out;
  float* hst = out;
  float* cst = out + (long)NBATCH * T_STEPS * HID;
  float* ost = out + 2L * NBATCH * T_STEPS * HID;

  char* base = (char*)d_ws;
  size_t off = 0;
  auto carve = [&](size_t bytes) -> char* {
    char* r = base + off;
    off = (off + bytes + 255) & ~(size_t)255;
    return r;
  };
  short* Wbig = (short*)carve(4096L * KTOT * 2);      // 16 MB (tiled)
  short* Wfcb = (short*)carve(1024L * 1024 * 2);      // 2 MB
  float* b0r  = (float*)carve(4096 * 4);
  float* bcr  = (float*)carve(4096 * 4);
  short* xb0  = (short*)carve((long)NBATCH * KTOT * 2);   // 1 MB (tiled)
  short* xb1  = (short*)carve((long)NBATCH * KTOT * 2);   // 1 MB (tiled)
  unsigned* ctr = (unsigned*)carve(512);              // 4 barrier counters

  hipMemsetAsync(ctr, 0, 512, stream);
  cast_kernel<<<5632, 256, 0, stream>>>(W_hh, W_fc, cvec, Wbig, Wfcb, xb0);
  bias_kernel<<<1024, 256, 0, stream>>>(W_ih, b_ih, b_hh, b_fc, b0r, bcr);
  wc_kernel<<<4096, 256, 0, stream>>>(W_ih, W_fc, Wbig);

  lstm_kernel<<<256, 512, 0, stream>>>(Wbig, b0r, bcr, cvec,
                                       xb0, xb1, hst, cst, ctr);

  fc_kernel<<<4096, 256, 0, stream>>>(cst, Wfcb, b_fc, ost);
}